// Round 9
// baseline (353.887 us; speedup 1.0000x reference)
//
#include <hip/hip_runtime.h>
#include <hip/hip_bf16.h>

#define B_    4
#define S_    512
#define NS_   8192
#define MAXW  16
#define H_    256
#define NH_   4
#define FF_   1024
#define NSPAN (B_*NS_)
#define NEGV  (-1.0e9f)
#define MT    64

typedef short s16x8 __attribute__((ext_vector_type(8)));
typedef float f32x16 __attribute__((ext_vector_type(16)));

__device__ __forceinline__ unsigned short f2bu(float v){
  __hip_bfloat16 h = __float2bfloat16(v);
  union { __hip_bfloat16 h; unsigned short u; } c; c.h = h; return c.u;
}
__device__ __forceinline__ float bu2f(unsigned short u){
  union { unsigned int i; float f; } c; c.i = ((unsigned int)u) << 16; return c.f;
}
__device__ __forceinline__ f32x16 MFMA32(s16x8 a, s16x8 b, f32x16 c){
  return __builtin_amdgcn_mfma_f32_32x32x16_bf16(a, b, c, 0, 0, 0);
}

// ---- prep_q: 4 blocks (one per head) ----
__global__ __launch_bounds__(256) void prep_q_kernel(
    const float* __restrict__ dq, const float* __restrict__ wq,
    const float* __restrict__ wk, const float* __restrict__ bqkv,
    float* __restrict__ qkvec, float* __restrict__ qb)
{
  __shared__ float q_s[H_];
  const int t = threadIdx.x;
  const int h = blockIdx.x;
  float acc = bqkv[t];
  const float4* wr = (const float4*)(wq + (size_t)t*H_);
  #pragma unroll 8
  for (int c = 0; c < 64; ++c) {
    float4 u = wr[c];
    float4 d = *(const float4*)(dq + c*4);
    acc += u.x*d.x + u.y*d.y + u.z*d.z + u.w*d.w;
  }
  q_s[t] = acc;
  __syncthreads();
  float s = 0.f;
  #pragma unroll 8
  for (int d = 0; d < 64; ++d) s += q_s[h*64 + d] * wk[(size_t)(h*64 + d)*H_ + t];
  qkvec[h*H_ + t] = s;
  if (t < 64) {
    float p = q_s[h*64 + t] * bqkv[H_ + h*64 + t];
    #pragma unroll
    for (int off = 32; off; off >>= 1) p += __shfl_down(p, off);
    if (t == 0) qb[h] = p;
  }
}

// ---- prep_all: [0,2048) trbf+logits; [2048,3072) W1T; [3072,4096) W2T;
//                [4096,4352) Wcomb; 4352 zbias ----
__global__ __launch_bounds__(256) void prep_all_kernel(
    const float* __restrict__ tok, const float* __restrict__ qkvec,
    const float* __restrict__ qb,
    const float* __restrict__ wv, const float* __restrict__ wo,
    const float* __restrict__ bqkv, const float* __restrict__ bo,
    const float* __restrict__ dq,
    const float* __restrict__ w1, const float* __restrict__ w2,
    unsigned short* __restrict__ trbf,
    float* __restrict__ lt, unsigned short* __restrict__ wct,
    unsigned short* __restrict__ w1t, unsigned short* __restrict__ w2t,
    float* __restrict__ zbias)
{
  const int blk = blockIdx.x;
  const int t = threadIdx.x;
  if (blk < 2048) {
    __shared__ float red[4][4];
    const int row = blk;
    const int p = row & (S_ - 1);
    float fac = expf((float)((t >> 1)*2) * (-9.210340371976184f / 256.0f));
    float ang = (float)p * fac;
    float pe = (t & 1) ? cosf(ang) : sinf(ang);
    float v = tok[(size_t)row*H_ + t] + pe;
    trbf[(size_t)row*H_ + t] = f2bu(v);
    float p0 = qkvec[t]*v, p1 = qkvec[H_+t]*v, p2 = qkvec[2*H_+t]*v, p3 = qkvec[3*H_+t]*v;
    const int l = t & 63, wv_ = t >> 6;
    #pragma unroll
    for (int m = 1; m < 64; m <<= 1) {
      p0 += __shfl_xor(p0, m); p1 += __shfl_xor(p1, m);
      p2 += __shfl_xor(p2, m); p3 += __shfl_xor(p3, m);
    }
    if (l == 0) { red[wv_][0]=p0; red[wv_][1]=p1; red[wv_][2]=p2; red[wv_][3]=p3; }
    __syncthreads();
    if (t < 4)
      lt[row*NH_ + t] = (red[0][t]+red[1][t]+red[2][t]+red[3][t] + qb[t]) * 0.125f;
  } else if (blk < 3072) {
    int idx = (blk - 2048)*256 + t;
    int n = idx >> 8, k = idx & 255;
    w1t[idx] = f2bu(w1[(size_t)k*FF_ + n]);
  } else if (blk < 4096) {
    int idx = (blk - 3072)*256 + t;
    int n = idx >> 10, k = idx & 1023;
    w2t[idx] = f2bu(w2[(size_t)k*H_ + n]);
  } else if (blk < 4352) {
    __shared__ float wo_s[H_];
    const int i = blk - 4096;
    wo_s[t] = wo[(size_t)i*H_ + t];
    __syncthreads();
    #pragma unroll
    for (int h = 0; h < NH_; ++h) {
      float s = 0.f;
      #pragma unroll 8
      for (int d = 0; d < 64; ++d)
        s += wo_s[h*64 + d] * wv[(size_t)(h*64 + d)*H_ + t];
      wct[(size_t)i*1024 + h*H_ + t] = f2bu(s);
    }
  } else {
    __shared__ float bv_s[H_];
    bv_s[t] = bqkv[2*H_ + t];
    __syncthreads();
    float acc = bo[t] + dq[t];
    const float4* wr = (const float4*)(wo + (size_t)t*H_);
    #pragma unroll 8
    for (int c = 0; c < 64; ++c) {
      float4 u = wr[c];
      acc += u.x*bv_s[c*4] + u.y*bv_s[c*4+1] + u.z*bv_s[c*4+2] + u.w*bv_s[c*4+3];
    }
    zbias[t] = acc;
  }
}

// ---- fused: pool (2 heads/pass) + Z-GEMM + LN1 + FFN + LN2 + mask -> out ----
// 512 thr = 8 waves; 32x32x16 MFMA; each wave owns 32 output cols, all 64 rows.
__global__ __launch_bounds__(512, 4) void fused_kernel(
    const unsigned short* __restrict__ trbf, const float* __restrict__ lt,
    const int* __restrict__ span_ids, const int* __restrict__ span_masks,
    const unsigned short* __restrict__ wct, const float* __restrict__ zbias,
    const unsigned short* __restrict__ w1t, const float* __restrict__ b1,
    const unsigned short* __restrict__ w2t, const float* __restrict__ b2,
    const float* __restrict__ lng, const float* __restrict__ lnb,
    float* __restrict__ out)
{
  __shared__ __align__(16) unsigned short bufA[MT*256];  // 32 KB
  __shared__ __align__(16) unsigned short bufY[MT*256];  // 32 KB
  __shared__ float attn_s[2][MT][16];                    // 8 KB
  __shared__ float part_s[MT][8][2];                     // 4 KB
  __shared__ float mv_s[MT][2];                          // 512 B
  __shared__ int meta_rb[MT];
  __shared__ int meta_len[MT];
  __shared__ int meta_mk[MT];

  const int t  = threadIdx.x;
  const int l  = t & 63;
  const int wv = t >> 6;          // 0..7 (column-group)
  const int lh = l & 31;
  const int hs = l >> 5;          // half-select
  const int sw = (lh & 7) << 4;   // A-read swizzle (row&7 == lh&7 for rows lh, lh+32)
  const int m0 = blockIdx.x * MT;
  const int col = wv*32 + lh;     // this lane's output column (per 256-col chunk)

  if (t < MT) {
    int gs = m0 + t;
    int st = span_ids[gs*2];
    int en = span_ids[gs*2 + 1];
    int mk = span_masks[gs];
    meta_rb[t]  = (gs >> 13) * S_ + st;
    meta_len[t] = mk ? (en - st) : 0;
    meta_mk[t]  = mk;
  }
  __syncthreads();

  const f32x16 Z16 = {0,0,0,0,0,0,0,0,0,0,0,0,0,0,0,0};

  auto attn_pass = [&](int p){
    #pragma unroll
    for (int q = 0; q < 4; ++q) {
      int slot = q*512 + t;
      int w  = slot & 15;
      int sp = (slot >> 4) & 63;
      int h2 = slot >> 10;
      int rb = meta_rb[sp], len = meta_len[sp];
      float lg_ = (w < len) ? lt[(rb + w)*NH_ + p*2 + h2] : NEGV;
      float mx = lg_;
      mx = fmaxf(mx, __shfl_xor(mx,1));
      mx = fmaxf(mx, __shfl_xor(mx,2));
      mx = fmaxf(mx, __shfl_xor(mx,4));
      mx = fmaxf(mx, __shfl_xor(mx,8));
      float e = expf(lg_ - mx);
      float se = e;
      se += __shfl_xor(se,1); se += __shfl_xor(se,2);
      se += __shfl_xor(se,4); se += __shfl_xor(se,8);
      attn_s[h2][sp][w] = e / se;
    }
  };

  auto pool_pass = [&](){
    #pragma unroll 1
    for (int i = 0; i < 8; ++i) {
      int sp = wv*8 + i;
      int rb = meta_rb[sp];
      const ushort4* p4 = (const ushort4*)(trbf + (size_t)rb*H_) + l;
      float a0=0,a1=0,a2=0,a3=0, c0=0,c1=0,c2=0,c3=0;
      #pragma unroll
      for (int w2 = 0; w2 < MAXW; ++w2) {
        ushort4 xv = p4[w2*64];
        float av0 = attn_s[0][sp][w2];
        float av1 = attn_s[1][sp][w2];
        float x0=bu2f(xv.x), x1=bu2f(xv.y), x2=bu2f(xv.z), x3=bu2f(xv.w);
        a0 += av0*x0; a1 += av0*x1; a2 += av0*x2; a3 += av0*x3;
        c0 += av1*x0; c1 += av1*x1; c2 += av1*x2; c3 += av1*x3;
      }
      int off = sp*512 + ((l*8) ^ ((sp&7)<<4));
      ushort4 o0, o1;
      o0.x=f2bu(a0); o0.y=f2bu(a1); o0.z=f2bu(a2); o0.w=f2bu(a3);
      o1.x=f2bu(c0); o1.y=f2bu(c1); o1.z=f2bu(c2); o1.w=f2bu(c3);
      *(ushort4*)((char*)bufA + off) = o0;
      *(ushort4*)((char*)bufY + off) = o1;
    }
  };

  // K=256 GEMM: A = 64x256 swizzled LDS tile, B = [n][k] global, 3-deep prefetch
  auto gemm = [&](const unsigned short* buf, const unsigned short* bmat,
                  int kstride, int kbase, f32x16& ac0, f32x16& ac1){
    const unsigned short* bp = bmat + (size_t)col*kstride + kbase + hs*8;
    s16x8 b0 = *(const s16x8*)bp;
    s16x8 b1 = *(const s16x8*)(bp + 16);
    s16x8 b2 = *(const s16x8*)(bp + 32);
    #pragma unroll
    for (int s = 0; s < 16; ++s) {
      s16x8 bn = b2;
      if (s < 13) bn = *(const s16x8*)(bp + (s+3)*16);
      int cb = (s*32 + hs*16) ^ sw;
      s16x8 a0 = *(const s16x8*)((const char*)buf + lh*512 + cb);
      s16x8 a1 = *(const s16x8*)((const char*)buf + (lh+32)*512 + cb);
      ac0 = MFMA32(a0, b0, ac0);
      ac1 = MFMA32(a1, b0, ac1);
      b0 = b1; b1 = b2; b2 = bn;
    }
  };

  // ---- Z phase ----
  f32x16 acc0 = Z16, acc1 = Z16;
  attn_pass(0);
  __syncthreads();
  pool_pass();                       // heads 0,1 -> bufA, bufY
  __syncthreads();
  attn_pass(1);                      // overlaps with gemms (attn_s free)
  gemm(bufA, wct, 1024, 0,   acc0, acc1);
  gemm(bufY, wct, 1024, 256, acc0, acc1);
  __syncthreads();
  pool_pass();                       // heads 2,3 -> bufA, bufY
  __syncthreads();
  gemm(bufA, wct, 1024, 512, acc0, acc1);
  gemm(bufY, wct, 1024, 768, acc0, acc1);
  __syncthreads();                   // bufY free for y

  // ---- LN1 -> y in bufY ----
  const float zbv = zbias[col];
  const float gv  = lng[col];
  const float bv  = lnb[col];
  #pragma unroll
  for (int mf = 0; mf < 2; ++mf)
    #pragma unroll
    for (int r = 0; r < 16; ++r) {
      float v = (mf ? acc1[r] : acc0[r]) + zbv;
      float s1 = v, s2 = v*v;
      s1 += __shfl_xor(s1,1);  s2 += __shfl_xor(s2,1);
      s1 += __shfl_xor(s1,2);  s2 += __shfl_xor(s2,2);
      s1 += __shfl_xor(s1,4);  s2 += __shfl_xor(s2,4);
      s1 += __shfl_xor(s1,8);  s2 += __shfl_xor(s2,8);
      s1 += __shfl_xor(s1,16); s2 += __shfl_xor(s2,16);
      if (lh == 0) {
        int row = mf*32 + (r&3) + ((r>>2)<<3) + hs*4;
        part_s[row][wv][0] = s1; part_s[row][wv][1] = s2;
      }
    }
  __syncthreads();
  {
    int row = t >> 3, j = t & 7;
    float s1 = part_s[row][j][0], s2 = part_s[row][j][1];
    s1 += __shfl_xor(s1,1); s2 += __shfl_xor(s2,1);
    s1 += __shfl_xor(s1,2); s2 += __shfl_xor(s2,2);
    s1 += __shfl_xor(s1,4); s2 += __shfl_xor(s2,4);
    if (j == 0) {
      float mean = s1 * (1.f/H_);
      float var  = s2 * (1.f/H_) - mean*mean; var = fmaxf(var, 0.f);
      mv_s[row][0] = mean; mv_s[row][1] = rsqrtf(var + 1e-5f);
    }
  }
  __syncthreads();
  #pragma unroll
  for (int mf = 0; mf < 2; ++mf)
    #pragma unroll
    for (int r = 0; r < 16; ++r) {
      int row = mf*32 + (r&3) + ((r>>2)<<3) + hs*4;
      float v = (mf ? acc1[r] : acc0[r]) + zbv;
      float y = (v - mv_s[row][0]) * mv_s[row][1] * gv + bv;
      int off = row*512 + ((col*2) ^ ((row&7)<<4));
      *(unsigned short*)((char*)bufY + off) = f2bu(y);
    }
  __syncthreads();

  // ---- FFN ----
  f32x16 f20 = Z16, f21 = Z16;
  #pragma unroll 1
  for (int nc = 0; nc < 4; ++nc) {
    f32x16 a0c = Z16, a1c = Z16;
    gemm(bufY, w1t + (size_t)(nc*256)*256, 256, 0, a0c, a1c);
    __syncthreads();                 // prior FFN2 readers of bufA done
    const float b1v = b1[nc*256 + col];
    #pragma unroll
    for (int mf = 0; mf < 2; ++mf)
      #pragma unroll
      for (int r = 0; r < 16; ++r) {
        int row = mf*32 + (r&3) + ((r>>2)<<3) + hs*4;
        float v = fmaxf((mf ? a1c[r] : a0c[r]) + b1v, 0.f);
        int off = row*512 + ((col*2) ^ ((row&7)<<4));
        *(unsigned short*)((char*)bufA + off) = f2bu(v);
      }
    __syncthreads();
    gemm(bufA, w2t, 1024, nc*256, f20, f21);
  }

  // ---- LN2 + residual + mask -> out ----
  const float b2v = b2[col];
  #pragma unroll
  for (int mf = 0; mf < 2; ++mf)
    #pragma unroll
    for (int r = 0; r < 16; ++r) {
      int row = mf*32 + (r&3) + ((r>>2)<<3) + hs*4;
      int off = row*512 + ((col*2) ^ ((row&7)<<4));
      float rd = bu2f(*(const unsigned short*)((const char*)bufY + off));
      float v = (mf ? f21[r] : f20[r]) + b2v + rd;
      float s1 = v, s2 = v*v;
      s1 += __shfl_xor(s1,1);  s2 += __shfl_xor(s2,1);
      s1 += __shfl_xor(s1,2);  s2 += __shfl_xor(s2,2);
      s1 += __shfl_xor(s1,4);  s2 += __shfl_xor(s2,4);
      s1 += __shfl_xor(s1,8);  s2 += __shfl_xor(s2,8);
      s1 += __shfl_xor(s1,16); s2 += __shfl_xor(s2,16);
      if (lh == 0) { part_s[row][wv][0] = s1; part_s[row][wv][1] = s2; }
    }
  __syncthreads();
  {
    int row = t >> 3, j = t & 7;
    float s1 = part_s[row][j][0], s2 = part_s[row][j][1];
    s1 += __shfl_xor(s1,1); s2 += __shfl_xor(s2,1);
    s1 += __shfl_xor(s1,2); s2 += __shfl_xor(s2,2);
    s1 += __shfl_xor(s1,4); s2 += __shfl_xor(s2,4);
    if (j == 0) {
      float mean = s1 * (1.f/H_);
      float var  = s2 * (1.f/H_) - mean*mean; var = fmaxf(var, 0.f);
      mv_s[row][0] = mean; mv_s[row][1] = rsqrtf(var + 1e-5f);
    }
  }
  __syncthreads();
  #pragma unroll
  for (int mf = 0; mf < 2; ++mf)
    #pragma unroll
    for (int r = 0; r < 16; ++r) {
      int row = mf*32 + (r&3) + ((r>>2)<<3) + hs*4;
      int off = row*512 + ((col*2) ^ ((row&7)<<4));
      float rd = bu2f(*(const unsigned short*)((const char*)bufY + off));
      float v = (mf ? f21[r] : f20[r]) + b2v + rd;
      float o = (v - mv_s[row][0]) * mv_s[row][1] * gv + bv;
      out[(size_t)(m0 + row)*H_ + col] = meta_mk[row] ? o : 0.f;
    }
}

extern "C" void kernel_launch(void* const* d_in, const int* in_sizes, int n_in,
                              void* d_out, int out_size, void* d_ws, size_t ws_size,
                              hipStream_t stream) {
  const float* tok      = (const float*)d_in[0];
  const int* span_ids   = (const int*)d_in[1];
  const int* span_masks = (const int*)d_in[2];
  const float* dq   = (const float*)d_in[4];
  const float* wq   = (const float*)d_in[5];
  const float* wk   = (const float*)d_in[6];
  const float* wv   = (const float*)d_in[7];
  const float* bqkv = (const float*)d_in[8];
  const float* wo   = (const float*)d_in[9];
  const float* bo   = (const float*)d_in[10];
  const float* lng  = (const float*)d_in[11];
  const float* lnb  = (const float*)d_in[12];
  const float* w1   = (const float*)d_in[13];
  const float* b1   = (const float*)d_in[14];
  const float* w2   = (const float*)d_in[15];
  const float* b2   = (const float*)d_in[16];

  float* ws    = (float*)d_ws;
  float* qkvec = ws;                         // 1024 f
  float* qbuf  = qkvec + 1024;               // 8 f
  float* lt    = qbuf + 8;                   // 8192 f
  float* zbias = lt + 8192;                  // 256 f
  unsigned short* ub = (unsigned short*)(zbias + 256);
  unsigned short* trbf = ub;                 // 524288
  unsigned short* wct  = trbf + 524288;      // 262144
  unsigned short* w1t  = wct + 262144;       // 262144
  unsigned short* w2t  = w1t + 262144;       // 262144

  hipLaunchKernelGGL(prep_q_kernel, dim3(NH_), dim3(256), 0, stream,
                     dq, wq, wk, bqkv, qkvec, qbuf);
  hipLaunchKernelGGL(prep_all_kernel, dim3(4353), dim3(256), 0, stream,
                     tok, qkvec, qbuf, wv, wo, bqkv, bo, dq, w1, w2,
                     trbf, lt, wct, w1t, w2t, zbias);
  hipLaunchKernelGGL(fused_kernel, dim3(NSPAN/MT), dim3(512), 0, stream,
                     trbf, lt, span_ids, span_masks, wct, zbias,
                     w1t, b1, w2t, b2, lng, lnb, (float*)d_out);
}